// Round 4
// baseline (422.049 us; speedup 1.0000x reference)
//
#include <hip/hip_runtime.h>

#define M_TOT 37440      // B*T*N_VALID = 96*390
#define N_E   768
#define K_TOT 672        // C*PH*PW = 4*14*12
#define NV    390
#define GWID  26
#define PHh   14
#define PWw   12
#define IMW   312
#define CSTRIDE 131040   // 420*312
#define NSTRIDE 524160   // 4*420*312

#define NKT   7          // K tiles of 96
#define ROWP  104        // padded row: 96 data + 8 pad (208 B = 52 dwords -> full bank spread)

typedef short bf16x8 __attribute__((ext_vector_type(8)));
typedef float f32x4  __attribute__((ext_vector_type(4)));
typedef unsigned short u16;
typedef u16 u16x4 __attribute__((ext_vector_type(4)));

// ws layout: A_pad[7][37440][104] u16, then W_pad[7][768][104] u16
#define A_PAD_BYTES 54512640u                 // 7*37440*104*2
#define W_PAD_BYTES 1118208u                  // 7*768*104*2
#define WS_NEEDED   (A_PAD_BYTES + W_PAD_BYTES)

#define NBLK_A 8190                           // 37440*56/256
#define NBLK_W 168                            // 768*56/256

static __device__ __forceinline__ u16 f2bf(float f) {
  unsigned u = __builtin_bit_cast(unsigned, f);
  u = (u + 0x7FFFu + ((u >> 16) & 1u)) >> 16;   // RNE
  return (u16)u;
}

#define GLOAD_LDS16(g, l) \
  __builtin_amdgcn_global_load_lds((const __attribute__((address_space(1))) void*)(g), \
                                   (__attribute__((address_space(3))) void*)(l), 16, 0, 0)

// ---------------- Kernel 1: patchify x -> A_pad, convert W -> W_pad (K-tiled, padded rows) ----
__global__ __launch_bounds__(256) void patchify(
    const float* __restrict__ x, const float* __restrict__ w,
    const int* __restrict__ valid, u16* __restrict__ Ap, u16* __restrict__ Wp) {
  const int bid = blockIdx.x;
  const int tid = threadIdx.x;
  if (bid < NBLK_A) {
    const int g  = bid * 256 + tid;          // run id, < 2096640
    const int m  = g / 56;
    const int rr = g - m * 56;               // 0..55
    const int t  = rr >> 3, run = rr & 7;
    const int nimg = m / NV;
    const int v    = m - nimg * NV;
    const int gidx = valid[v];
    const int gi = gidx / GWID, gj = gidx - gi * GWID;
    const int c  = rr / PHh,    p  = rr - c * PHh;
    const float* src = x + (size_t)nimg * NSTRIDE + (size_t)c * CSTRIDE
                         + (size_t)(gi * PHh + p) * IMW + gj * PWw;
    f32x4 f0 = *(const f32x4*)(src + 0);
    f32x4 f1 = *(const f32x4*)(src + 4);
    f32x4 f2 = *(const f32x4*)(src + 8);
    u16* dst = Ap + ((size_t)(t * M_TOT + m)) * ROWP + run * 12;
    u16x4 h0 = {f2bf(f0.x), f2bf(f0.y), f2bf(f0.z), f2bf(f0.w)};
    u16x4 h1 = {f2bf(f1.x), f2bf(f1.y), f2bf(f1.z), f2bf(f1.w)};
    u16x4 h2 = {f2bf(f2.x), f2bf(f2.y), f2bf(f2.z), f2bf(f2.w)};
    *(u16x4*)(dst + 0) = h0;
    *(u16x4*)(dst + 4) = h1;
    *(u16x4*)(dst + 8) = h2;
  } else {
    const int g  = (bid - NBLK_A) * 256 + tid;   // < 43008
    const int n  = g / 56;
    const int rr = g - n * 56;
    const int t  = rr >> 3, run = rr & 7;
    const float* src = w + (size_t)n * K_TOT + rr * 12;
    f32x4 f0 = *(const f32x4*)(src + 0);
    f32x4 f1 = *(const f32x4*)(src + 4);
    f32x4 f2 = *(const f32x4*)(src + 8);
    u16* dst = Wp + ((size_t)(t * N_E + n)) * ROWP + run * 12;
    u16x4 h0 = {f2bf(f0.x), f2bf(f0.y), f2bf(f0.z), f2bf(f0.w)};
    u16x4 h1 = {f2bf(f1.x), f2bf(f1.y), f2bf(f1.z), f2bf(f1.w)};
    u16x4 h2 = {f2bf(f2.x), f2bf(f2.y), f2bf(f2.z), f2bf(f2.w)};
    *(u16x4*)(dst + 0) = h0;
    *(u16x4*)(dst + 4) = h1;
    *(u16x4*)(dst + 8) = h2;
  }
}

// ---------------- Kernel 2: dense bf16 GEMM, 128x128, BK=96, double-buffered 2-phase ----------
// C[M][768] = A[M][672] * W[768][672]^T + bias
__global__ __launch_bounds__(256) void gemm_bf16(
    const u16* __restrict__ Ap, const u16* __restrict__ Wp,
    const float* __restrict__ bias, float* __restrict__ out) {
  // [buf][mat][128 rows * 104 elems] : 106,496 B total
  __shared__ u16 lds[2][2][128 * ROWP];

  const int tid  = threadIdx.x;
  const int lane = tid & 63;
  const int wid  = tid >> 6;
  const int wr   = wid >> 1, wc = wid & 1;
  const int lrow = lane & 15, lhi = lane >> 4;

  const int n0 = blockIdx.x * 128;   // 6 n-tiles fastest -> L3 reuse of A
  const int m0 = blockIdx.y * 128;   // 293 m-tiles

  // stage one K-tile t into buffer b: 52 chunks of 1024 B (26 A + 26 B), 13 per wave.
  // waves 0,1 -> A ; waves 2,3 -> B. LDS dest is wave-uniform (HW adds lane*16).
  auto STAGE = [&](int t, int b) {
    if (wid < 2) {
      const u16* srcb = Ap + ((size_t)(t * M_TOT + m0)) * ROWP + lane * 8;
      #pragma unroll
      for (int j = 0; j < 13; ++j) {
        const int c = wid * 13 + j;                    // 0..25
        GLOAD_LDS16(srcb + c * 512, (char*)&lds[b][0][0] + c * 1024);
      }
    } else {
      const u16* srcb = Wp + ((size_t)(t * N_E + n0)) * ROWP + lane * 8;
      #pragma unroll
      for (int j = 0; j < 13; ++j) {
        const int c = (wid - 2) * 13 + j;              // 0..25
        GLOAD_LDS16(srcb + c * 512, (char*)&lds[b][1][0] + c * 1024);
      }
    }
  };

  f32x4 acc[4][4];
  #pragma unroll
  for (int i = 0; i < 4; ++i)
    #pragma unroll
    for (int j = 0; j < 4; ++j)
      acc[i][j] = (f32x4){0.f, 0.f, 0.f, 0.f};

  STAGE(0, 0);                        // prologue

  for (int t = 0; t < NKT; ++t) {
    const int b = t & 1;
    if (t < NKT - 1) {
      STAGE(t + 1, b ^ 1);            // 13 more in flight per wave
      asm volatile("s_waitcnt vmcnt(13)" ::: "memory");   // tile t's 13 landed
    } else {
      asm volatile("s_waitcnt vmcnt(0)" ::: "memory");
    }
    __builtin_amdgcn_s_barrier();     // raw: no compiler vmcnt(0) drain

    #pragma unroll
    for (int kk = 0; kk < 3; ++kk) {
      bf16x8 a[4], bfr[4];
      #pragma unroll
      for (int i = 0; i < 4; ++i)
        a[i] = *(const bf16x8*)&lds[b][0][(wr * 64 + i * 16 + lrow) * ROWP + kk * 32 + lhi * 8];
      #pragma unroll
      for (int j = 0; j < 4; ++j)
        bfr[j] = *(const bf16x8*)&lds[b][1][(wc * 64 + j * 16 + lrow) * ROWP + kk * 32 + lhi * 8];
      #pragma unroll
      for (int i = 0; i < 4; ++i)
        #pragma unroll
        for (int j = 0; j < 4; ++j)
          acc[i][j] = __builtin_amdgcn_mfma_f32_16x16x32_bf16(a[i], bfr[j], acc[i][j], 0, 0, 0);
    }
    asm volatile("" ::: "memory");    // pin LDS reads above this point
    __builtin_amdgcn_s_barrier();     // buf consumed; next STAGE may overwrite
  }

  float bv[4];
  #pragma unroll
  for (int j = 0; j < 4; ++j)
    bv[j] = bias[n0 + wc * 64 + j * 16 + lrow];

  #pragma unroll
  for (int i = 0; i < 4; ++i) {
    const int mbase = m0 + wr * 64 + i * 16 + lhi * 4;
    #pragma unroll
    for (int j = 0; j < 4; ++j) {
      const int e = n0 + wc * 64 + j * 16 + lrow;
      float* op = out + (size_t)mbase * N_E + e;
      #pragma unroll
      for (int tt = 0; tt < 4; ++tt) {
        if (mbase + tt < M_TOT) op[(size_t)tt * N_E] = acc[i][j][tt] + bv[j];
      }
    }
  }
}

// ---------------- Fallback (round-1 fused kernel) if ws too small ----------------
#define ROWB 104
__global__ __launch_bounds__(256) void patch_gemm_fused(
    const float* __restrict__ x, const float* __restrict__ w,
    const float* __restrict__ bias, const int* __restrict__ valid,
    float* __restrict__ out) {
  __shared__ u16 Alds[128 * ROWB];
  __shared__ u16 Blds[128 * ROWB];
  const int tid  = threadIdx.x;
  const int lane = tid & 63;
  const int wid  = tid >> 6;
  const int wr   = wid >> 1, wc = wid & 1;
  const int lrow = lane & 15, lhi = lane >> 4;
  const int m0 = blockIdx.x * 128;
  const int n0 = blockIdx.y * 128;
  const int arow = tid & 127;
  int m = m0 + arow;
  if (m >= M_TOT) m = M_TOT - 1;
  const int nimg = m / NV;
  const int v    = m - nimg * NV;
  const int g    = valid[v];
  const int gi   = g / GWID;
  const int gj   = g - gi * GWID;
  const float* xrow = x + (size_t)nimg * NSTRIDE + (size_t)(gi * PHh) * IMW + gj * PWw;
  const int half = tid >> 7;
  const float* wrow = w + (size_t)(n0 + arow) * K_TOT;
  f32x4 acc[4][4];
  #pragma unroll
  for (int i = 0; i < 4; ++i)
    #pragma unroll
    for (int j = 0; j < 4; ++j)
      acc[i][j] = (f32x4){0.f, 0.f, 0.f, 0.f};
  for (int t = 0; t < 7; ++t) {
    #pragma unroll
    for (int it = 0; it < 4; ++it) {
      const int run = half + it * 2;
      const int rr  = t * 8 + run;
      const int c   = rr / PHh;
      const int p   = rr - c * PHh;
      const float* src = xrow + (size_t)c * CSTRIDE + p * IMW;
      f32x4 f0 = *(const f32x4*)(src + 0);
      f32x4 f1 = *(const f32x4*)(src + 4);
      f32x4 f2 = *(const f32x4*)(src + 8);
      u16x4 h0 = {f2bf(f0.x), f2bf(f0.y), f2bf(f0.z), f2bf(f0.w)};
      u16x4 h1 = {f2bf(f1.x), f2bf(f1.y), f2bf(f1.z), f2bf(f1.w)};
      u16x4 h2 = {f2bf(f2.x), f2bf(f2.y), f2bf(f2.z), f2bf(f2.w)};
      u16* dst = &Alds[arow * ROWB + run * 12];
      *(u16x4*)(dst + 0) = h0;
      *(u16x4*)(dst + 4) = h1;
      *(u16x4*)(dst + 8) = h2;
    }
    #pragma unroll
    for (int i = 0; i < 6; ++i) {
      const int col = half * 48 + i * 8;
      const float* src = wrow + t * 96 + col;
      f32x4 f0 = *(const f32x4*)(src + 0);
      f32x4 f1 = *(const f32x4*)(src + 4);
      u16x4 h0 = {f2bf(f0.x), f2bf(f0.y), f2bf(f0.z), f2bf(f0.w)};
      u16x4 h1 = {f2bf(f1.x), f2bf(f1.y), f2bf(f1.z), f2bf(f1.w)};
      u16* dst = &Blds[arow * ROWB + col];
      *(u16x4*)(dst + 0) = h0;
      *(u16x4*)(dst + 4) = h1;
    }
    __syncthreads();
    #pragma unroll
    for (int kk = 0; kk < 3; ++kk) {
      bf16x8 a[4], b[4];
      #pragma unroll
      for (int i = 0; i < 4; ++i)
        a[i] = *(const bf16x8*)&Alds[(wr * 64 + i * 16 + lrow) * ROWB + kk * 32 + lhi * 8];
      #pragma unroll
      for (int j = 0; j < 4; ++j)
        b[j] = *(const bf16x8*)&Blds[(wc * 64 + j * 16 + lrow) * ROWB + kk * 32 + lhi * 8];
      #pragma unroll
      for (int i = 0; i < 4; ++i)
        #pragma unroll
        for (int j = 0; j < 4; ++j)
          acc[i][j] = __builtin_amdgcn_mfma_f32_16x16x32_bf16(a[i], b[j], acc[i][j], 0, 0, 0);
    }
    __syncthreads();
  }
  float bv[4];
  #pragma unroll
  for (int j = 0; j < 4; ++j)
    bv[j] = bias[n0 + wc * 64 + j * 16 + lrow];
  #pragma unroll
  for (int i = 0; i < 4; ++i) {
    const int mbase = m0 + wr * 64 + i * 16 + lhi * 4;
    #pragma unroll
    for (int j = 0; j < 4; ++j) {
      const int e = n0 + wc * 64 + j * 16 + lrow;
      float* op = out + (size_t)mbase * N_E + e;
      #pragma unroll
      for (int tt = 0; tt < 4; ++tt) {
        if (mbase + tt < M_TOT) op[(size_t)tt * N_E] = acc[i][j][tt] + bv[j];
      }
    }
  }
}

extern "C" void kernel_launch(void* const* d_in, const int* in_sizes, int n_in,
                              void* d_out, int out_size, void* d_ws, size_t ws_size,
                              hipStream_t stream) {
  const float* x     = (const float*)d_in[0];
  const float* w     = (const float*)d_in[1];
  const float* b     = (const float*)d_in[2];
  const int*   valid = (const int*)d_in[3];
  float* out = (float*)d_out;

  if (ws_size >= (size_t)WS_NEEDED) {
    u16* Aws = (u16*)d_ws;
    u16* Wws = (u16*)((char*)d_ws + A_PAD_BYTES);
    patchify<<<NBLK_A + NBLK_W, 256, 0, stream>>>(x, w, valid, Aws, Wws);
    dim3 grid(N_E / 128, (M_TOT + 127) / 128);   // 6 x 293, n fastest
    gemm_bf16<<<grid, dim3(256), 0, stream>>>(Aws, Wws, b, out);
  } else {
    dim3 grid((M_TOT + 127) / 128, N_E / 128);
    patch_gemm_fused<<<grid, dim3(256), 0, stream>>>(x, w, b, valid, out);
  }
}

// Round 5
// 384.815 us; speedup vs baseline: 1.0968x; 1.0968x over previous
//
#include <hip/hip_runtime.h>

#define M_TOT 37440      // B*T*N_VALID = 96*390
#define N_E   768
#define K_TOT 672        // C*PH*PW = 4*14*12
#define NV    390
#define GWID  26
#define PHh   14
#define PWw   12
#define IMW   312
#define CSTRIDE 131040   // 420*312
#define NSTRIDE 524160   // 4*420*312

#define NKT   7          // K tiles of 96
#define TPAD  104        // padded K-tile: 96 data + 8 pad (208 B = 52 dw = full bank spread)
#define ROWT  728        // 7*104 elems per padded row

typedef short bf16x8 __attribute__((ext_vector_type(8)));
typedef float f32x4  __attribute__((ext_vector_type(4)));
typedef unsigned short u16;
typedef u16 u16x4 __attribute__((ext_vector_type(4)));

// ws: A_pad[37440][728] u16, then W_pad[768][728] u16
#define A_PAD_BYTES 54512640u                 // 37440*728*2
#define W_PAD_BYTES 1118208u                  // 768*728*2
#define WS_NEEDED   (A_PAD_BYTES + W_PAD_BYTES)

#define NBLK_A 8190                           // 37440*56/256
#define NBLK_W 168                            // 768*56/256

#define NWG   1758                            // 6 * 293
#define SWZ_Q 219                             // 1758 = 8*219 + 6
#define SWZ_R 6

static __device__ __forceinline__ u16 f2bf(float f) {
  unsigned u = __builtin_bit_cast(unsigned, f);
  u = (u + 0x7FFFu + ((u >> 16) & 1u)) >> 16;   // RNE
  return (u16)u;
}

#define GLOAD_LDS16(g, l) \
  __builtin_amdgcn_global_load_lds((const __attribute__((address_space(1))) void*)(g), \
                                   (__attribute__((address_space(3))) void*)(l), 16, 0, 0)

// ---------------- Kernel 1: patchify x -> A_pad[M][728], W -> W_pad[768][728] ----------------
// Row layout: tile t occupies [t*104, t*104+96) data; contiguous 24B writes per thread.
__global__ __launch_bounds__(256) void patchify(
    const float* __restrict__ x, const float* __restrict__ w,
    const int* __restrict__ valid, u16* __restrict__ Ap, u16* __restrict__ Wp) {
  const int bid = blockIdx.x;
  const int tid = threadIdx.x;
  if (bid < NBLK_A) {
    const int g  = bid * 256 + tid;          // run id, < 2096640
    const int m  = g / 56;
    const int rr = g - m * 56;               // 0..55
    const int t  = rr >> 3, run = rr & 7;
    const int nimg = m / NV;
    const int v    = m - nimg * NV;
    const int gidx = valid[v];
    const int gi = gidx / GWID, gj = gidx - gi * GWID;
    const int c  = rr / PHh,    p  = rr - c * PHh;
    const float* src = x + (size_t)nimg * NSTRIDE + (size_t)c * CSTRIDE
                         + (size_t)(gi * PHh + p) * IMW + gj * PWw;
    f32x4 f0 = *(const f32x4*)(src + 0);
    f32x4 f1 = *(const f32x4*)(src + 4);
    f32x4 f2 = *(const f32x4*)(src + 8);
    u16* dst = Ap + (size_t)m * ROWT + t * TPAD + run * 12;
    u16x4 h0 = {f2bf(f0.x), f2bf(f0.y), f2bf(f0.z), f2bf(f0.w)};
    u16x4 h1 = {f2bf(f1.x), f2bf(f1.y), f2bf(f1.z), f2bf(f1.w)};
    u16x4 h2 = {f2bf(f2.x), f2bf(f2.y), f2bf(f2.z), f2bf(f2.w)};
    *(u16x4*)(dst + 0) = h0;
    *(u16x4*)(dst + 4) = h1;
    *(u16x4*)(dst + 8) = h2;
  } else {
    const int g  = (bid - NBLK_A) * 256 + tid;   // < 43008
    const int n  = g / 56;
    const int rr = g - n * 56;
    const int t  = rr >> 3, run = rr & 7;
    const float* src = w + (size_t)n * K_TOT + rr * 12;
    f32x4 f0 = *(const f32x4*)(src + 0);
    f32x4 f1 = *(const f32x4*)(src + 4);
    f32x4 f2 = *(const f32x4*)(src + 8);
    u16* dst = Wp + (size_t)n * ROWT + t * TPAD + run * 12;
    u16x4 h0 = {f2bf(f0.x), f2bf(f0.y), f2bf(f0.z), f2bf(f0.w)};
    u16x4 h1 = {f2bf(f1.x), f2bf(f1.y), f2bf(f1.z), f2bf(f1.w)};
    u16x4 h2 = {f2bf(f2.x), f2bf(f2.y), f2bf(f2.z), f2bf(f2.w)};
    *(u16x4*)(dst + 0) = h0;
    *(u16x4*)(dst + 4) = h1;
    *(u16x4*)(dst + 8) = h2;
  }
}

// ---------------- Kernel 2: dense bf16 GEMM, 128x128, BK=96, single-buffer, 3 blocks/CU ------
__global__ __launch_bounds__(256, 3) void gemm_bf16(
    const u16* __restrict__ Ap, const u16* __restrict__ Wp,
    const float* __restrict__ bias, float* __restrict__ out) {
  __shared__ u16 lds[2][128 * TPAD];   // 53,248 B -> 3 blocks/CU

  const int tid  = threadIdx.x;
  const int lane = tid & 63;
  const int wid  = tid >> 6;
  const int wr   = wid >> 1, wc = wid & 1;
  const int lrow = lane & 15, lhi = lane >> 4;

  // XCD-chunked bijective swizzle: XCD x owns a contiguous run of logical ids,
  // so the 6 n-blocks sharing one A-panel hit the same XCD L2.
  const int orig = blockIdx.x;
  const int xcd = orig & 7, pos = orig >> 3;
  const int lid = (xcd < SWZ_R ? xcd * (SWZ_Q + 1)
                               : SWZ_R * (SWZ_Q + 1) + (xcd - SWZ_R) * SWZ_Q) + pos;
  const int n0 = (lid % 6) * 128;     // n fastest
  const int m0 = (lid / 6) * 128;

  // staging: 26 A chunks (waves 0,1) + 26 W chunks (waves 2,3), 13 chunks/wave,
  // chunk = 1024B = 64 lanes x 16B. LDS linear == [row][104] since 13*16B = one row.
  int goff[13];
  const u16* gbase;
  if (wid < 2) {
    #pragma unroll
    for (int j = 0; j < 13; ++j) {
      const int g = (wid * 13 + j) * 64 + lane;
      const int row = g / 13, col = g - row * 13;
      int ar = m0 + row; if (ar > M_TOT - 1) ar = M_TOT - 1;   // tail clamp
      goff[j] = ar * ROWT + col * 8;
    }
    gbase = Ap;
  } else {
    #pragma unroll
    for (int j = 0; j < 13; ++j) {
      const int g = ((wid - 2) * 13 + j) * 64 + lane;
      const int row = g / 13, col = g - row * 13;
      goff[j] = (n0 + row) * ROWT + col * 8;
    }
    gbase = Wp;
  }
  char* ldst = (char*)&lds[wid >> 1][0] + (wid & 1) * (13 * 1024);

  f32x4 acc[4][4];
  #pragma unroll
  for (int i = 0; i < 4; ++i)
    #pragma unroll
    for (int j = 0; j < 4; ++j)
      acc[i][j] = (f32x4){0.f, 0.f, 0.f, 0.f};

  for (int t = 0; t < NKT; ++t) {
    #pragma unroll
    for (int j = 0; j < 13; ++j)
      GLOAD_LDS16(gbase + goff[j] + t * TPAD, ldst + j * 1024);
    __syncthreads();                  // drains vmcnt; cross-block overlap hides it

    #pragma unroll
    for (int kk = 0; kk < 3; ++kk) {
      bf16x8 a[4], bfr[4];
      #pragma unroll
      for (int i = 0; i < 4; ++i)
        a[i] = *(const bf16x8*)&lds[0][(wr * 64 + i * 16 + lrow) * TPAD + kk * 32 + lhi * 8];
      #pragma unroll
      for (int j = 0; j < 4; ++j)
        bfr[j] = *(const bf16x8*)&lds[1][(wc * 64 + j * 16 + lrow) * TPAD + kk * 32 + lhi * 8];
      #pragma unroll
      for (int i = 0; i < 4; ++i)
        #pragma unroll
        for (int j = 0; j < 4; ++j)
          acc[i][j] = __builtin_amdgcn_mfma_f32_16x16x32_bf16(a[i], bfr[j], acc[i][j], 0, 0, 0);
    }
    __syncthreads();                  // buf consumed; next stage may overwrite
  }

  float bv[4];
  #pragma unroll
  for (int j = 0; j < 4; ++j)
    bv[j] = bias[n0 + wc * 64 + j * 16 + lrow];

  #pragma unroll
  for (int i = 0; i < 4; ++i) {
    const int mbase = m0 + wr * 64 + i * 16 + lhi * 4;
    #pragma unroll
    for (int j = 0; j < 4; ++j) {
      const int e = n0 + wc * 64 + j * 16 + lrow;
      float* op = out + (size_t)mbase * N_E + e;
      #pragma unroll
      for (int tt = 0; tt < 4; ++tt) {
        if (mbase + tt < M_TOT) op[(size_t)tt * N_E] = acc[i][j][tt] + bv[j];
      }
    }
  }
}

// ---------------- Fallback (round-1 fused kernel) if ws too small ----------------
#define ROWB 104
__global__ __launch_bounds__(256) void patch_gemm_fused(
    const float* __restrict__ x, const float* __restrict__ w,
    const float* __restrict__ bias, const int* __restrict__ valid,
    float* __restrict__ out) {
  __shared__ u16 Alds[128 * ROWB];
  __shared__ u16 Blds[128 * ROWB];
  const int tid  = threadIdx.x;
  const int lane = tid & 63;
  const int wid  = tid >> 6;
  const int wr   = wid >> 1, wc = wid & 1;
  const int lrow = lane & 15, lhi = lane >> 4;
  const int m0 = blockIdx.x * 128;
  const int n0 = blockIdx.y * 128;
  const int arow = tid & 127;
  int m = m0 + arow;
  if (m >= M_TOT) m = M_TOT - 1;
  const int nimg = m / NV;
  const int v    = m - nimg * NV;
  const int g    = valid[v];
  const int gi   = g / GWID;
  const int gj   = g - gi * GWID;
  const float* xrow = x + (size_t)nimg * NSTRIDE + (size_t)(gi * PHh) * IMW + gj * PWw;
  const int half = tid >> 7;
  const float* wrow = w + (size_t)(n0 + arow) * K_TOT;
  f32x4 acc[4][4];
  #pragma unroll
  for (int i = 0; i < 4; ++i)
    #pragma unroll
    for (int j = 0; j < 4; ++j)
      acc[i][j] = (f32x4){0.f, 0.f, 0.f, 0.f};
  for (int t = 0; t < 7; ++t) {
    #pragma unroll
    for (int it = 0; it < 4; ++it) {
      const int run = half + it * 2;
      const int rr  = t * 8 + run;
      const int c   = rr / PHh;
      const int p   = rr - c * PHh;
      const float* src = xrow + (size_t)c * CSTRIDE + p * IMW;
      f32x4 f0 = *(const f32x4*)(src + 0);
      f32x4 f1 = *(const f32x4*)(src + 4);
      f32x4 f2 = *(const f32x4*)(src + 8);
      u16x4 h0 = {f2bf(f0.x), f2bf(f0.y), f2bf(f0.z), f2bf(f0.w)};
      u16x4 h1 = {f2bf(f1.x), f2bf(f1.y), f2bf(f1.z), f2bf(f1.w)};
      u16x4 h2 = {f2bf(f2.x), f2bf(f2.y), f2bf(f2.z), f2bf(f2.w)};
      u16* dst = &Alds[arow * ROWB + run * 12];
      *(u16x4*)(dst + 0) = h0;
      *(u16x4*)(dst + 4) = h1;
      *(u16x4*)(dst + 8) = h2;
    }
    #pragma unroll
    for (int i = 0; i < 6; ++i) {
      const int col = half * 48 + i * 8;
      const float* src = wrow + t * 96 + col;
      f32x4 f0 = *(const f32x4*)(src + 0);
      f32x4 f1 = *(const f32x4*)(src + 4);
      u16x4 h0 = {f2bf(f0.x), f2bf(f0.y), f2bf(f0.z), f2bf(f0.w)};
      u16x4 h1 = {f2bf(f1.x), f2bf(f1.y), f2bf(f1.z), f2bf(f1.w)};
      u16* dst = &Blds[arow * ROWB + col];
      *(u16x4*)(dst + 0) = h0;
      *(u16x4*)(dst + 4) = h1;
    }
    __syncthreads();
    #pragma unroll
    for (int kk = 0; kk < 3; ++kk) {
      bf16x8 a[4], b[4];
      #pragma unroll
      for (int i = 0; i < 4; ++i)
        a[i] = *(const bf16x8*)&Alds[(wr * 64 + i * 16 + lrow) * ROWB + kk * 32 + lhi * 8];
      #pragma unroll
      for (int j = 0; j < 4; ++j)
        b[j] = *(const bf16x8*)&Blds[(wc * 64 + j * 16 + lrow) * ROWB + kk * 32 + lhi * 8];
      #pragma unroll
      for (int i = 0; i < 4; ++i)
        #pragma unroll
        for (int j = 0; j < 4; ++j)
          acc[i][j] = __builtin_amdgcn_mfma_f32_16x16x32_bf16(a[i], b[j], acc[i][j], 0, 0, 0);
    }
    __syncthreads();
  }
  float bv[4];
  #pragma unroll
  for (int j = 0; j < 4; ++j)
    bv[j] = bias[n0 + wc * 64 + j * 16 + lrow];
  #pragma unroll
  for (int i = 0; i < 4; ++i) {
    const int mbase = m0 + wr * 64 + i * 16 + lhi * 4;
    #pragma unroll
    for (int j = 0; j < 4; ++j) {
      const int e = n0 + wc * 64 + j * 16 + lrow;
      float* op = out + (size_t)mbase * N_E + e;
      #pragma unroll
      for (int tt = 0; tt < 4; ++tt) {
        if (mbase + tt < M_TOT) op[(size_t)tt * N_E] = acc[i][j][tt] + bv[j];
      }
    }
  }
}

extern "C" void kernel_launch(void* const* d_in, const int* in_sizes, int n_in,
                              void* d_out, int out_size, void* d_ws, size_t ws_size,
                              hipStream_t stream) {
  const float* x     = (const float*)d_in[0];
  const float* w     = (const float*)d_in[1];
  const float* b     = (const float*)d_in[2];
  const int*   valid = (const int*)d_in[3];
  float* out = (float*)d_out;

  if (ws_size >= (size_t)WS_NEEDED) {
    u16* Aws = (u16*)d_ws;
    u16* Wws = (u16*)((char*)d_ws + A_PAD_BYTES);
    patchify<<<NBLK_A + NBLK_W, 256, 0, stream>>>(x, w, valid, Aws, Wws);
    gemm_bf16<<<NWG, 256, 0, stream>>>(Aws, Wws, b, out);
  } else {
    dim3 grid((M_TOT + 127) / 128, N_E / 128);
    patch_gemm_fused<<<grid, dim3(256), 0, stream>>>(x, w, b, valid, out);
  }
}

// Round 7
// 376.818 us; speedup vs baseline: 1.1200x; 1.0212x over previous
//
#include <hip/hip_runtime.h>

#define M_TOT 37440      // B*T*N_VALID = 96*390
#define N_E   768
#define K_TOT 672        // C*PH*PW = 4*14*12
#define NV    390
#define GWID  26
#define PHh   14
#define PWw   12
#define IMW   312
#define CSTRIDE 131040   // 420*312
#define NSTRIDE 524160   // 4*420*312

#define NKT   7          // K tiles of 96
#define TPAD  104        // padded K-tile: 96 data + 8 pad (208 B = 52 dw -> full bank spread)
#define ROWT  728        // 7*104 elems per padded row

typedef short bf16x8 __attribute__((ext_vector_type(8)));
typedef float f32x4  __attribute__((ext_vector_type(4)));
typedef unsigned short u16;
typedef u16 u16x4 __attribute__((ext_vector_type(4)));

// ws: A_pad[37440][728] u16, then W_pad[768][728] u16
#define A_PAD_BYTES 54512640u                 // 37440*728*2
#define W_PAD_BYTES 1118208u                  // 768*728*2
#define WS_NEEDED   (A_PAD_BYTES + W_PAD_BYTES)

#define NBLK_A 8190                           // 37440*56/256
#define NBLK_W 168                            // 768*56/256

// gemm grid: BM=256 -> 147 m-tiles, BN=128 -> 6 n-tiles
#define NWG   882                             // 147*6
#define SWZ_Q 110                             // 882 = 8*110 + 2
#define SWZ_R 2

static __device__ __forceinline__ u16 f2bf(float f) {
  unsigned u = __builtin_bit_cast(unsigned, f);
  u = (u + 0x7FFFu + ((u >> 16) & 1u)) >> 16;   // RNE
  return (u16)u;
}

#define GLOAD_LDS16(g, l) \
  __builtin_amdgcn_global_load_lds((const __attribute__((address_space(1))) void*)(g), \
                                   (__attribute__((address_space(3))) void*)(l), 16, 0, 0)

// ---------------- Kernel 1: patchify x -> A_pad[M][728], W -> W_pad[768][728] ----------------
__global__ __launch_bounds__(256) void patchify(
    const float* __restrict__ x, const float* __restrict__ w,
    const int* __restrict__ valid, u16* __restrict__ Ap, u16* __restrict__ Wp) {
  const int bid = blockIdx.x;
  const int tid = threadIdx.x;
  if (bid < NBLK_A) {
    const int g  = bid * 256 + tid;          // run id, < 2096640
    const int m  = g / 56;
    const int rr = g - m * 56;               // 0..55
    const int t  = rr >> 3, run = rr & 7;
    const int nimg = m / NV;
    const int v    = m - nimg * NV;
    const int gidx = valid[v];
    const int gi = gidx / GWID, gj = gidx - gi * GWID;
    const int c  = rr / PHh,    p  = rr - c * PHh;
    const float* src = x + (size_t)nimg * NSTRIDE + (size_t)c * CSTRIDE
                         + (size_t)(gi * PHh + p) * IMW + gj * PWw;
    f32x4 f0 = *(const f32x4*)(src + 0);
    f32x4 f1 = *(const f32x4*)(src + 4);
    f32x4 f2 = *(const f32x4*)(src + 8);
    u16* dst = Ap + (size_t)m * ROWT + t * TPAD + run * 12;
    u16x4 h0 = {f2bf(f0.x), f2bf(f0.y), f2bf(f0.z), f2bf(f0.w)};
    u16x4 h1 = {f2bf(f1.x), f2bf(f1.y), f2bf(f1.z), f2bf(f1.w)};
    u16x4 h2 = {f2bf(f2.x), f2bf(f2.y), f2bf(f2.z), f2bf(f2.w)};
    *(u16x4*)(dst + 0) = h0;
    *(u16x4*)(dst + 4) = h1;
    *(u16x4*)(dst + 8) = h2;
  } else {
    const int g  = (bid - NBLK_A) * 256 + tid;   // < 43008
    const int n  = g / 56;
    const int rr = g - n * 56;
    const int t  = rr >> 3, run = rr & 7;
    const float* src = w + (size_t)n * K_TOT + rr * 12;
    f32x4 f0 = *(const f32x4*)(src + 0);
    f32x4 f1 = *(const f32x4*)(src + 4);
    f32x4 f2 = *(const f32x4*)(src + 8);
    u16* dst = Wp + (size_t)n * ROWT + t * TPAD + run * 12;
    u16x4 h0 = {f2bf(f0.x), f2bf(f0.y), f2bf(f0.z), f2bf(f0.w)};
    u16x4 h1 = {f2bf(f1.x), f2bf(f1.y), f2bf(f1.z), f2bf(f1.w)};
    u16x4 h2 = {f2bf(f2.x), f2bf(f2.y), f2bf(f2.z), f2bf(f2.w)};
    *(u16x4*)(dst + 0) = h0;
    *(u16x4*)(dst + 4) = h1;
    *(u16x4*)(dst + 8) = h2;
  }
}

// ---------------- Kernel 2: bf16 GEMM, 256x128 tile, 512 thr, BK=96, 2 blocks/CU -------------
// C[M][768] = A[M][672] * W[768][672]^T + bias
__global__ __launch_bounds__(512, 4) void gemm_bf16(
    const u16* __restrict__ Ap, const u16* __restrict__ Wp,
    const float* __restrict__ bias, float* __restrict__ out) {
  // A: 256 rows * 208B = 53,248B (52 chunks); W: 128 rows * 208B = 26,624B (26 chunks)
  __shared__ u16 lds[384 * TPAD];   // 79,872 B -> 2 blocks/CU
  u16* Awlds = &lds[0];
  u16* Wwlds = &lds[256 * TPAD];

  const int tid  = threadIdx.x;
  const int lane = tid & 63;
  const int wid  = tid >> 6;          // 0..7
  const int wr   = wid >> 1;          // 0..3 : m sub-tile (64 rows)
  const int wc   = wid & 1;           // 0..1 : e sub-tile (64 cols)
  const int lrow = lane & 15, lhi = lane >> 4;

  // bijective XCD-chunked swizzle (882 = 8*110 + 2)
  const int orig = blockIdx.x;
  const int xcd = orig & 7, pos = orig >> 3;
  const int lid = (xcd < SWZ_R ? xcd * (SWZ_Q + 1)
                               : SWZ_R * (SWZ_Q + 1) + (xcd - SWZ_R) * SWZ_Q) + pos;
  const int n0 = (lid % 6) * 128;     // n fastest -> A-panel L2/L3 reuse
  const int m0 = (lid / 6) * 256;

  // staging: 78 chunks of 1024B, round-robin c = j*8 + wid (wave-uniform).
  // chunk c<52 -> A region; else W region. LDS linear == padded [row][104] rows.
  int goff[10];
  #pragma unroll
  for (int j = 0; j < 10; ++j) {
    const int c = j * 8 + wid;
    if (c < 52) {
      const int idx = c * 64 + lane;            // 16B unit within A region
      const int row = idx / 13, col = idx - row * 13;
      int ar = m0 + row; if (ar > M_TOT - 1) ar = M_TOT - 1;   // tail clamp
      goff[j] = ar * ROWT + col * 8;
    } else if (c < 78) {
      const int idx = (c - 52) * 64 + lane;
      const int row = idx / 13, col = idx - row * 13;
      goff[j] = (n0 + row) * ROWT + col * 8;
    } else {
      goff[j] = 0;
    }
  }

  f32x4 acc[4][4];
  #pragma unroll
  for (int i = 0; i < 4; ++i)
    #pragma unroll
    for (int j = 0; j < 4; ++j)
      acc[i][j] = (f32x4){0.f, 0.f, 0.f, 0.f};

  for (int t = 0; t < NKT; ++t) {
    #pragma unroll
    for (int j = 0; j < 10; ++j) {
      const int c = j * 8 + wid;                // wave-uniform
      if (c < 52) {
        GLOAD_LDS16(Ap + goff[j] + t * TPAD, (char*)Awlds + c * 1024);
      } else if (c < 78) {
        GLOAD_LDS16(Wp + goff[j] + t * TPAD, (char*)Wwlds + (c - 52) * 1024);
      }
    }
    __syncthreads();

    #pragma unroll
    for (int kk = 0; kk < 3; ++kk) {
      bf16x8 a[4], bfr[4];
      #pragma unroll
      for (int i = 0; i < 4; ++i)
        a[i] = *(const bf16x8*)&Awlds[(wr * 64 + i * 16 + lrow) * TPAD + kk * 32 + lhi * 8];
      #pragma unroll
      for (int j = 0; j < 4; ++j)
        bfr[j] = *(const bf16x8*)&Wwlds[(wc * 64 + j * 16 + lrow) * TPAD + kk * 32 + lhi * 8];
      // swapped operands: D col(lane&15)=m, row-regs = 4 consecutive e -> dwordx4 stores
      #pragma unroll
      for (int i = 0; i < 4; ++i)
        #pragma unroll
        for (int j = 0; j < 4; ++j)
          acc[i][j] = __builtin_amdgcn_mfma_f32_16x16x32_bf16(bfr[j], a[i], acc[i][j], 0, 0, 0);
    }
    __syncthreads();
  }

  // epilogue: lane holds m = m0+wr*64+i*16+lrow, e0 = n0+wc*64+j*16+lhi*4 (+reg)
  f32x4 bv[4];
  #pragma unroll
  for (int j = 0; j < 4; ++j)
    bv[j] = *(const f32x4*)&bias[n0 + wc * 64 + j * 16 + lhi * 4];

  #pragma unroll
  for (int i = 0; i < 4; ++i) {
    const int m = m0 + wr * 64 + i * 16 + lrow;
    if (m < M_TOT) {
      float* orow = out + (size_t)m * N_E + n0 + wc * 64 + lhi * 4;
      #pragma unroll
      for (int j = 0; j < 4; ++j) {
        f32x4 v = acc[i][j] + bv[j];
        *(f32x4*)(orow + j * 16) = v;
      }
    }
  }
}

// ---------------- Fallback (round-1 fused kernel) if ws too small ----------------
#define ROWB 104
__global__ __launch_bounds__(256) void patch_gemm_fused(
    const float* __restrict__ x, const float* __restrict__ w,
    const float* __restrict__ bias, const int* __restrict__ valid,
    float* __restrict__ out) {
  __shared__ u16 Alds[128 * ROWB];
  __shared__ u16 Blds[128 * ROWB];
  const int tid  = threadIdx.x;
  const int lane = tid & 63;
  const int wid  = tid >> 6;
  const int wr   = wid >> 1, wc = wid & 1;
  const int lrow = lane & 15, lhi = lane >> 4;
  const int m0 = blockIdx.x * 128;
  const int n0 = blockIdx.y * 128;
  const int arow = tid & 127;
  int m = m0 + arow;
  if (m >= M_TOT) m = M_TOT - 1;
  const int nimg = m / NV;
  const int v    = m - nimg * NV;
  const int g    = valid[v];
  const int gi   = g / GWID;
  const int gj   = g - gi * GWID;
  const float* xrow = x + (size_t)nimg * NSTRIDE + (size_t)(gi * PHh) * IMW + gj * PWw;
  const int half = tid >> 7;
  const float* wrow = w + (size_t)(n0 + arow) * K_TOT;
  f32x4 acc[4][4];
  #pragma unroll
  for (int i = 0; i < 4; ++i)
    #pragma unroll
    for (int j = 0; j < 4; ++j)
      acc[i][j] = (f32x4){0.f, 0.f, 0.f, 0.f};
  for (int t = 0; t < 7; ++t) {
    #pragma unroll
    for (int it = 0; it < 4; ++it) {
      const int run = half + it * 2;
      const int rr  = t * 8 + run;
      const int c   = rr / PHh;
      const int p   = rr - c * PHh;
      const float* src = xrow + (size_t)c * CSTRIDE + p * IMW;
      f32x4 f0 = *(const f32x4*)(src + 0);
      f32x4 f1 = *(const f32x4*)(src + 4);
      f32x4 f2 = *(const f32x4*)(src + 8);
      u16x4 h0 = {f2bf(f0.x), f2bf(f0.y), f2bf(f0.z), f2bf(f0.w)};
      u16x4 h1 = {f2bf(f1.x), f2bf(f1.y), f2bf(f1.z), f2bf(f1.w)};
      u16x4 h2 = {f2bf(f2.x), f2bf(f2.y), f2bf(f2.z), f2bf(f2.w)};
      u16* dst = &Alds[arow * ROWB + run * 12];
      *(u16x4*)(dst + 0) = h0;
      *(u16x4*)(dst + 4) = h1;
      *(u16x4*)(dst + 8) = h2;
    }
    #pragma unroll
    for (int i = 0; i < 6; ++i) {
      const int col = half * 48 + i * 8;
      const float* src = wrow + t * 96 + col;
      f32x4 f0 = *(const f32x4*)(src + 0);
      f32x4 f1 = *(const f32x4*)(src + 4);
      u16x4 h0 = {f2bf(f0.x), f2bf(f0.y), f2bf(f0.z), f2bf(f0.w)};
      u16x4 h1 = {f2bf(f1.x), f2bf(f1.y), f2bf(f1.z), f2bf(f1.w)};
      u16* dst = &Blds[arow * ROWB + col];
      *(u16x4*)(dst + 0) = h0;
      *(u16x4*)(dst + 4) = h1;
    }
    __syncthreads();
    #pragma unroll
    for (int kk = 0; kk < 3; ++kk) {
      bf16x8 a[4], b[4];
      #pragma unroll
      for (int i = 0; i < 4; ++i)
        a[i] = *(const bf16x8*)&Alds[(wr * 64 + i * 16 + lrow) * ROWB + kk * 32 + lhi * 8];
      #pragma unroll
      for (int j = 0; j < 4; ++j)
        b[j] = *(const bf16x8*)&Blds[(wc * 64 + j * 16 + lrow) * ROWB + kk * 32 + lhi * 8];
      #pragma unroll
      for (int i = 0; i < 4; ++i)
        #pragma unroll
        for (int j = 0; j < 4; ++j)
          acc[i][j] = __builtin_amdgcn_mfma_f32_16x16x32_bf16(a[i], b[j], acc[i][j], 0, 0, 0);
    }
    __syncthreads();
  }
  float bv[4];
  #pragma unroll
  for (int j = 0; j < 4; ++j)
    bv[j] = bias[n0 + wc * 64 + j * 16 + lrow];
  #pragma unroll
  for (int i = 0; i < 4; ++i) {
    const int mbase = m0 + wr * 64 + i * 16 + lhi * 4;
    #pragma unroll
    for (int j = 0; j < 4; ++j) {
      const int e = n0 + wc * 64 + j * 16 + lrow;
      float* op = out + (size_t)mbase * N_E + e;
      #pragma unroll
      for (int tt = 0; tt < 4; ++tt) {
        if (mbase + tt < M_TOT) op[(size_t)tt * N_E] = acc[i][j][tt] + bv[j];
      }
    }
  }
}

extern "C" void kernel_launch(void* const* d_in, const int* in_sizes, int n_in,
                              void* d_out, int out_size, void* d_ws, size_t ws_size,
                              hipStream_t stream) {
  const float* x     = (const float*)d_in[0];
  const float* w     = (const float*)d_in[1];
  const float* b     = (const float*)d_in[2];
  const int*   valid = (const int*)d_in[3];
  float* out = (float*)d_out;

  if (ws_size >= (size_t)WS_NEEDED) {
    u16* Aws = (u16*)d_ws;
    u16* Wws = (u16*)((char*)d_ws + A_PAD_BYTES);
    patchify<<<NBLK_A + NBLK_W, 256, 0, stream>>>(x, w, valid, Aws, Wws);
    gemm_bf16<<<NWG, 512, 0, stream>>>(Aws, Wws, b, out);
  } else {
    dim3 grid((M_TOT + 127) / 128, N_E / 128);
    patch_gemm_fused<<<grid, dim3(256), 0, stream>>>(x, w, b, valid, out);
  }
}